// Round 2
// baseline (240.328 us; speedup 1.0000x reference)
//
#include <hip/hip_runtime.h>

// Problem constants (from reference)
constexpr int B     = 16384;
constexpr int NNEG  = 10;
constexpr int D     = 8;
constexpr int E     = 64;
constexpr int ROWS  = B * (1 + NNEG);   // 180224; flat row id == output index
constexpr int RPW   = 8;                // rows per wave (8-lane group per row)

// Sum of upper-triangular pairwise dots via 0.5*(||sum e||^2 - sum ||e||^2).
// Wave layout: lane l -> group g=l>>3 (row), t=l&7 owns dims [8t, 8t+8).
// Each gather instruction moves 64 lanes x 16B = 1KB across 8 rows; 16 loads
// in flight per wave (16KB) for latency hiding.
__global__ __launch_bounds__(256) void APE_61555471286335_kernel(
    const int*   __restrict__ pos_x,   // [B, D]
    const int*   __restrict__ neg_x,   // [B, NNEG, D]
    const float* __restrict__ emb,     // [N_ENT, E]
    const float* __restrict__ pair_w,  // [N_PAIRS]
    const float* __restrict__ c,       // [1]
    float*       __restrict__ out)     // [ROWS]
{
    const int tid  = blockIdx.x * blockDim.x + threadIdx.x;
    const int wave = tid >> 6;
    const int lane = threadIdx.x & 63;
    const int g    = lane >> 3;        // row within wave (0..7)
    const int t    = lane & 7;         // sub-lane within row group
    const int row  = wave * RPW + g;   // ROWS % (RPW*waves_per_block) == 0

    // 8 indices for this row as two int4 loads (rows are 32B-aligned).
    const int* idx = (row < B) ? (pos_x + (size_t)row * D)
                               : (neg_x + (size_t)(row - B) * D);
    const int4 i0 = *(const int4*)(idx);
    const int4 i1 = *(const int4*)(idx + 4);
    const int ids[D] = {i0.x, i0.y, i0.z, i0.w, i1.x, i1.y, i1.z, i1.w};

    float4 s0 = make_float4(0.f, 0.f, 0.f, 0.f), s1 = s0;  // per-dim sums
    float4 q0 = s0, q1 = s0;                               // per-dim sum of squares
#pragma unroll
    for (int d = 0; d < D; ++d) {
        const float* r = emb + (size_t)ids[d] * E + t * 8;
        const float4 v0 = *(const float4*)(r);
        const float4 v1 = *(const float4*)(r + 4);
        s0.x += v0.x; s0.y += v0.y; s0.z += v0.z; s0.w += v0.w;
        s1.x += v1.x; s1.y += v1.y; s1.z += v1.z; s1.w += v1.w;
        q0.x += v0.x * v0.x; q0.y += v0.y * v0.y;
        q0.z += v0.z * v0.z; q0.w += v0.w * v0.w;
        q1.x += v1.x * v1.x; q1.y += v1.y * v1.y;
        q1.z += v1.z * v1.z; q1.w += v1.w * v1.w;
    }

    // a = sum_l s_l^2 (partial over this lane's 8 dims), q = sum_l ss_l
    float a = s0.x * s0.x + s0.y * s0.y + s0.z * s0.z + s0.w * s0.w
            + s1.x * s1.x + s1.y * s1.y + s1.z * s1.z + s1.w * s1.w;
    float q = q0.x + q0.y + q0.z + q0.w + q1.x + q1.y + q1.z + q1.w;

    // Reduce across the 8-lane group (xor masks 4,2,1 stay within group).
#pragma unroll
    for (int off = 4; off > 0; off >>= 1) {
        a += __shfl_xor(a, off, 64);
        q += __shfl_xor(q, off, 64);
    }

    if (t == 0) {
        const float pair_sum = 0.5f * (a - q);
        out[row] = expf(pair_sum * expf(pair_w[0]) + c[0]);
    }
}

extern "C" void kernel_launch(void* const* d_in, const int* in_sizes, int n_in,
                              void* d_out, int out_size, void* d_ws, size_t ws_size,
                              hipStream_t stream) {
    const int*   pos_x  = (const int*)  d_in[0];
    const int*   neg_x  = (const int*)  d_in[1];
    const float* emb    = (const float*)d_in[2];
    const float* pair_w = (const float*)d_in[3];
    const float* c      = (const float*)d_in[4];
    float*       out    = (float*)      d_out;

    constexpr int BLOCK = 256;                       // 4 waves/block
    constexpr int ROWS_PER_BLOCK = (BLOCK / 64) * RPW;  // 32
    static_assert(ROWS % ROWS_PER_BLOCK == 0, "exact grid");
    const int grid = ROWS / ROWS_PER_BLOCK;          // 5632

    APE_61555471286335_kernel<<<grid, BLOCK, 0, stream>>>(
        pos_x, neg_x, emb, pair_w, c, out);
}

// Round 3
// 212.535 us; speedup vs baseline: 1.1308x; 1.1308x over previous
//
#include <hip/hip_runtime.h>

// Problem constants (from reference)
constexpr int B     = 16384;
constexpr int NNEG  = 10;
constexpr int D     = 8;
constexpr int E     = 64;               // == wavefront: lane l owns dim l
constexpr int ROWS  = B * (1 + NNEG);   // 180224; flat row id == output index
constexpr int RPW   = 4;                // rows per wave, processed in-register

// pair_sum = sum_{i<j} e_i.e_j = 0.5*(||sum_d e_d||^2 - sum_d ||e_d||^2).
// Layout identical to round 1 (lane = dim, each gather = one fully-coalesced
// 256B row read = 4 fully-consumed cache lines). MLP fix: 4 rows per wave,
// all 32 row-loads issued before any accumulation -> 8KB in flight per wave.
__global__ __launch_bounds__(256) void APE_61555471286335_kernel(
    const int*   __restrict__ pos_x,   // [B, D]
    const int*   __restrict__ neg_x,   // [B, NNEG, D]
    const float* __restrict__ emb,     // [N_ENT, E]
    const float* __restrict__ pair_w,  // [N_PAIRS]
    const float* __restrict__ c,       // [1]
    float*       __restrict__ out)     // [ROWS]
{
    const int tid  = blockIdx.x * blockDim.x + threadIdx.x;
    const int wave = tid >> 6;
    const int lane = threadIdx.x & 63;
    const int row0 = wave * RPW;       // ROWS % (RPW*4 waves) == 0, no bounds check

    // Gather all 4 rows x 8 dims = 32 values with loads issued back-to-back.
    float v[RPW][D];
#pragma unroll
    for (int r = 0; r < RPW; ++r) {
        const int row = row0 + r;
        const int* idx = (row < B) ? (pos_x + (size_t)row * D)
                                   : (neg_x + (size_t)(row - B) * D);
#pragma unroll
        for (int d = 0; d < D; ++d) {
            v[r][d] = emb[(size_t)idx[d] * E + lane];   // coalesced 256B
        }
    }

    // Per-row fused reduction value: p = s^2 - ss  (per-lane partial).
    float p[RPW];
#pragma unroll
    for (int r = 0; r < RPW; ++r) {
        float s = 0.f, ss = 0.f;
#pragma unroll
        for (int d = 0; d < D; ++d) {
            s  += v[r][d];
            ss += v[r][d] * v[r][d];
        }
        p[r] = s * s - ss;
    }

    // One butterfly per row; afterwards every lane holds the row's total.
#pragma unroll
    for (int off = 32; off > 0; off >>= 1) {
#pragma unroll
        for (int r = 0; r < RPW; ++r)
            p[r] += __shfl_xor(p[r], off, 64);
    }

    if (lane == 0) {
        const float w = expf(pair_w[0]);
        const float cc = c[0];
#pragma unroll
        for (int r = 0; r < RPW; ++r)
            out[row0 + r] = expf(0.5f * p[r] * w + cc);
    }
}

extern "C" void kernel_launch(void* const* d_in, const int* in_sizes, int n_in,
                              void* d_out, int out_size, void* d_ws, size_t ws_size,
                              hipStream_t stream) {
    const int*   pos_x  = (const int*)  d_in[0];
    const int*   neg_x  = (const int*)  d_in[1];
    const float* emb    = (const float*)d_in[2];
    const float* pair_w = (const float*)d_in[3];
    const float* c      = (const float*)d_in[4];
    float*       out    = (float*)      d_out;

    constexpr int BLOCK = 256;                          // 4 waves/block
    constexpr int ROWS_PER_BLOCK = (BLOCK / 64) * RPW;  // 16
    static_assert(ROWS % ROWS_PER_BLOCK == 0, "exact grid");
    const int grid = ROWS / ROWS_PER_BLOCK;             // 11264

    APE_61555471286335_kernel<<<grid, BLOCK, 0, stream>>>(
        pos_x, neg_x, emb, pair_w, c, out);
}